// Round 6
// baseline (469.684 us; speedup 1.0000x reference)
//
#include <hip/hip_runtime.h>
#include <hip/hip_bf16.h>
#include <stdint.h>

// Problem constants (from reference setup_inputs)
#define T_TOK 1024
#define K_IN  4096
#define N_OUT 6144
#define N_Q   4096
#define N_KV  1024
#define N_D   4
#define KP    512          // K_IN/8 packed int32 per row

// GEMM tiling
#define TM 64
#define TN 128
#define BK 64
#define NSTEPS (K_IN / BK)      // 64
#define PM_MAX 1280        // >= 1024 + 4*63 (worst-case 64-padding)
#define MT (PM_MAX/TM)     // 20
#define NT (N_OUT/TN)      // 48
#define NBLK (NT * MT)     // 960

// fused prep kernel block ranges (wbconv eliminated: base B staged fp32 in gemm)
#define NB_RP (48 * 4 * 2 * 8)             // 3072
#define NB_XP (PM_MAX * 2)                 // 2560

typedef __attribute__((ext_vector_type(8)))  short  short8;   // 8 x bf16 (4 VGPR) MFMA A/B frag
typedef __attribute__((ext_vector_type(4)))  float  float4v;  // MFMA C/D frag
typedef __attribute__((ext_vector_type(4)))  float  f32x4;
typedef __attribute__((ext_vector_type(4)))  uint   u32x4;

__device__ __forceinline__ ushort f2bf(float f) {
    uint32_t u = __float_as_uint(f);
    u = (u + 0x7FFFu + ((u >> 16) & 1u)) >> 16;   // RNE
    return (ushort)u;
}
__device__ __forceinline__ uint pack2(ushort a, ushort b) {
    return (uint)a | ((uint)b << 16);
}
// packed f32->bf16 RNE (hardware cvt_pk via HIP intrinsic)
__device__ __forceinline__ uint cvt2(float lo, float hi) {
    union { __hip_bfloat162 h2; uint u; } c;
    c.h2 = __float22bfloat162_rn(make_float2(lo, hi));
    return c.u;
}

// 8 nibbles of q -> short8 of bf16 values (128 + nib), exact.
// bf16 0x4300 = 128.0; mantissa has 7 bits so 128+n (n<=15) is exact.
// v_perm path: e.bj = n_{2j}, o.bj = n_{2j+1}; word j = [n2j, 0x43, n2j+1, 0x43]
// = perm(o, e, sel_j) | 0x43004300.  11 VALU per uint vs ~19 for shift/mask.
// The +128 offset and the GPTQ zero-point are corrected in the epilogue
// via the row-sum of A:  s*acc_nib - s*(129+z)*rowsum(A).
__device__ __forceinline__ short8 unpack_nib(uint q) {
    union { u32x4 u; short8 s; } r;
    uint e = q & 0x0F0F0F0Fu;          // even nibbles in byte lanes
    uint o = (q >> 4) & 0x0F0F0F0Fu;   // odd nibbles in byte lanes
    r.u.x = __builtin_amdgcn_perm(o, e, 0x0C040C00u) | 0x43004300u;
    r.u.y = __builtin_amdgcn_perm(o, e, 0x0C050C01u) | 0x43004300u;
    r.u.z = __builtin_amdgcn_perm(o, e, 0x0C060C02u) | 0x43004300u;
    r.u.w = __builtin_amdgcn_perm(o, e, 0x0C070C03u) | 0x43004300u;
    return r.s;
}

// ---------------------------------------------------------------------------
// K1: group tokens by adapter, fully parallel (1024 threads, one per token).
// perm[PM_MAX] = token index or -1 (padding); pofs[d] = padded segment starts
// (multiples of TM), pofs[N_D] = padded total.  Ballot-rank scatter: zero
// atomics, zero serial loops over tokens.
// ---------------------------------------------------------------------------
__global__ void build_perm_kernel(const int* __restrict__ indices,
                                  int* __restrict__ perm,
                                  int* __restrict__ pofs) {
    __shared__ int cw[16][4];   // per-wave counts
    __shared__ int pw[16][4];   // exclusive wave prefixes
    __shared__ int ps[N_D + 1];
    int tid = threadIdx.x;      // 1024 threads
    for (int p = tid; p < PM_MAX; p += 1024) perm[p] = -1;

    int d = indices[tid];
    unsigned long long m[4];
    m[0] = __ballot(d == 0); m[1] = __ballot(d == 1);
    m[2] = __ballot(d == 2); m[3] = __ballot(d == 3);
    int lane = tid & 63, wv = tid >> 6;
    if (lane < 4) cw[wv][lane] = (int)__popcll(m[lane]);
    __syncthreads();
    if (tid == 0) {
        int tot[4] = {0, 0, 0, 0};
        for (int w = 0; w < 16; w++)
            for (int dd = 0; dd < 4; dd++) { pw[w][dd] = tot[dd]; tot[dd] += cw[w][dd]; }
        int run = 0;
        for (int dd = 0; dd < N_D; dd++) { ps[dd] = run; run += ((tot[dd] + TM - 1) / TM) * TM; }
        ps[N_D] = run;
        for (int dd = 0; dd <= N_D; dd++) pofs[dd] = ps[dd];
    }
    __syncthreads();
    unsigned long long lt = (1ull << lane) - 1ull;
    int rank = pw[wv][d] + (int)__popcll(m[d] & lt);
    perm[ps[d] + rank] = tid;
}

// ---------------------------------------------------------------------------
// K2 (fused prep): two jobs partitioned by blockIdx range.
//  [0, NB_RP):     repack qw -> qp in GEMM-lane order     (100 MB)
//  [.., +NB_XP):   Xp[pm][k] = bf16(x[perm[pm]][k]) + row-sums rs
// ---------------------------------------------------------------------------
__global__ void prep_kernel(const int* __restrict__ qw_q, const int* __restrict__ qw_k,
                            const int* __restrict__ qw_v, uint* __restrict__ qp,
                            const float* __restrict__ x, const int* __restrict__ perm,
                            ushort* __restrict__ xp, float* __restrict__ rs) {
    __shared__ int slds[64 * 64];
    int tid = threadIdx.x;
    int b = blockIdx.x;

    if (b < NB_RP) {
        // ---- repack qw: qp[bn][d][w2][s][lane][8], block = (bn,d,w2,s8) ----
        int s8 = b & 7;
        int r  = b >> 3;
        int w2 = r & 1; r >>= 1;
        int d  = r & 3;
        int bn = r >> 2;
        const int* qw; int r0, Osec;
        if (bn < 32)      { qw = qw_q; r0 = bn * 128;        Osec = N_Q;  }
        else if (bn < 40) { qw = qw_k; r0 = (bn - 32) * 128; Osec = N_KV; }
        else              { qw = qw_v; r0 = (bn - 40) * 128; Osec = N_KV; }
#pragma unroll
        for (int k = 0; k < 4; k++) {
            int p   = k * 256 + tid;       // dwordx4 index [0,1024)
            int row = p >> 4, c4 = p & 15;
            const int* src = qw + ((size_t)d * Osec + r0 + w2 * 64 + row) * KP + s8 * 64 + c4 * 4;
            *(u32x4*)&slds[row * 64 + c4 * 4] = *(const u32x4*)src;
        }
        __syncthreads();
        size_t obase = (size_t)b * 4096;   // 4096 uints per block slab
#pragma unroll
        for (int k = 0; k < 2; k++) {
            int p    = k * 256 + tid;      // packet index [0,512)
            int sl   = p >> 6, lane = p & 63;
            int quad = lane >> 4, l16 = lane & 15;
            uint pk[8];
#pragma unroll
            for (int e = 0; e < 8; e++) {
                int jj = e >> 1, h = e & 1;
                pk[e] = (uint)slds[(jj * 16 + l16) * 64 + sl * 8 + h * 4 + quad];
            }
            *(u32x4*)(qp + obase + (size_t)p * 8)     = *(u32x4*)&pk[0];
            *(u32x4*)(qp + obase + (size_t)p * 8 + 4) = *(u32x4*)&pk[4];
        }
        return;
    }
    b -= NB_RP;
    {
        // ---- build_xp ----
        int pm = b >> 1;
        int half = b & 1;
        int c0 = half * (K_IN / 2) + tid * 8;
        int tok = perm[pm];
        ushort res[8];
        if (tok < 0) {
#pragma unroll
            for (int j = 0; j < 8; j++) res[j] = 0;
        } else {
            const f32x4* src = (const f32x4*)(x + (size_t)tok * K_IN + c0);
            f32x4 a = __builtin_nontemporal_load(src);
            f32x4 c = __builtin_nontemporal_load(src + 1);
            float v[8] = {a.x, a.y, a.z, a.w, c.x, c.y, c.z, c.w};
#pragma unroll
            for (int j = 0; j < 8; j++) res[j] = f2bf(v[j]);
        }
        u32x4 packv;
        packv.x = pack2(res[0], res[1]); packv.y = pack2(res[2], res[3]);
        packv.z = pack2(res[4], res[5]); packv.w = pack2(res[6], res[7]);
        *(u32x4*)(xp + (size_t)pm * K_IN + c0) = packv;

        // row-sum of the EXACT bf16 values the MFMA will consume
        float ssum = 0.f;
#pragma unroll
        for (int j = 0; j < 8; j++) ssum += __uint_as_float((uint)res[j] << 16);
#pragma unroll
        for (int off = 32; off > 0; off >>= 1) ssum += __shfl_xor(ssum, off);
        float* wsum = (float*)slds;
        if ((tid & 63) == 0) wsum[tid >> 6] = ssum;
        __syncthreads();
        if (tid == 0) rs[pm * 2 + half] = wsum[0] + wsum[1] + wsum[2] + wsum[3];
    }
}

// ---------------------------------------------------------------------------
// K3: full-K GEMM with fused GPTQ delta (no split-K, direct store).
// Base path: w_base staged DIRECTLY as fp32 into LDS (global_load_lds 16B).
// LDS swizzle: chunk ^= (row&7) on BOTH stage-source and read side -- same
// structure as the A-side that measures 0 bank conflicts: consecutive 8 lanes
// (l16=0..7) sweep all 8 bank groups.  (Round-5's (l16&7)<<1 variant aliased
// quad bits -> 1.4e7 conflicts; this is the fix.)  Frags read as 2 independent
// ds_read_b128 (c0^f, (c0+1)^f) and converted in-register via cvt_pk.
// Delta path: repacked qp packets, 2 coalesced dwordx4 per lane per step,
// prefetched one step ahead; unpacked with v_perm (11 VALU/uint).
// Epilogue: out = bias + acc_base + s*acc_nib - s*(129+z)*rowsumA.
// ---------------------------------------------------------------------------
__global__ __launch_bounds__(256, 2) void gemm_kernel(
    const ushort* __restrict__ xp, const float* __restrict__ w_base,
    const uint* __restrict__ qp,
    const int* __restrict__ qz_q, const int* __restrict__ qz_k, const int* __restrict__ qz_v,
    const float* __restrict__ sc_q, const float* __restrict__ sc_k, const float* __restrict__ sc_v,
    const float* __restrict__ bias,
    const int* __restrict__ perm, const int* __restrict__ pofs,
    const float* __restrict__ rs,
    float* __restrict__ out) {

    __shared__ ushort As[2][TM * BK];   // 2 x 8 KB  (bf16 A)
    __shared__ float  Bs[2][TN * BK];   // 2 x 32 KB (fp32 base B)

    // XCD-pinned decode: all blocks of one bn share lin%8 -> same XCD L2;
    // consecutive lin on an XCD iterate bm fastest -> same-bn blocks run
    // together -> the 2 MB fp32 w_base column stays L2-resident.
    int lin  = blockIdx.x;              // [0, 960)
    int low3 = lin & 7, rest = lin >> 3;
    int bm   = rest % MT, bq = rest / MT;
    int bn   = bq * 8 + low3;

    int m0 = bm * TM, n0 = bn * TN;
    int ptot = pofs[N_D];
    if (m0 >= ptot) return;                       // uniform per block
    int d = 0;
    while (d < N_D - 1 && m0 >= pofs[d + 1]) d++; // tile fully inside segment d

    int tid  = threadIdx.x;
    int lane = tid & 63;
    int wv   = tid >> 6;
    int wm   = (wv & 1) * 32;
    int wn   = (wv >> 1) * 64;
    int quad = lane >> 4;
    int l16  = lane & 15;
    int xa   = l16 & 7;          // read-side swizzle term (A: 8 chunks/row; B: 16 chunks/row)

    // delta packet base for this wave: qp[bn][d][w2][s][lane][8]
    const uint* qpw = qp + (((size_t)(bn * 4 + d) * 2 + (wv >> 1)) * 64 * 64 * 8)
                         + (size_t)lane * 8;

    const float4v zero4 = {0.f, 0.f, 0.f, 0.f};
    float4v acc_b[2][4], acc_d[2][4];
#pragma unroll
    for (int i = 0; i < 2; i++)
#pragma unroll
        for (int jj = 0; jj < 4; jj++) { acc_b[i][jj] = zero4; acc_d[i][jj] = zero4; }

    // stage one BK-tile (A bf16 + B fp32) into LDS; 16B/lane, chunk^(row&7)
    // swizzle on the global source (LDS dest stays linear per global_load_lds).
    auto stage = [&](ushort* dstA, float* dstB, int k0) {
#pragma unroll
        for (int w = 0; w < 2; w++) {
            int p   = w * 256 + tid;
            int row = p >> 3;
            int ckl = (p & 7) ^ (row & 7);
            const ushort* ga = xp + (size_t)(m0 + row) * K_IN + k0 + ckl * 8;
            int base = (w * 256 + (tid & ~63)) * 8;   // wave-uniform ushort offset
            __builtin_amdgcn_global_load_lds((const __attribute__((address_space(1))) void*)ga,
                                             (__attribute__((address_space(3))) void*)(dstA + base), 16, 0, 0);
        }
#pragma unroll
        for (int w = 0; w < 8; w++) {
            int p   = w * 256 + tid;
            int row = p >> 4;                          // [0,128)
            int ckl = (p & 15) ^ (row & 7);            // 16B chunk in 256B row
            const float* gb = w_base + (size_t)(n0 + row) * K_IN + k0 + ckl * 4;
            int base = (w * 256 + (tid & ~63)) * 4;    // wave-uniform float offset
            __builtin_amdgcn_global_load_lds((const __attribute__((address_space(1))) void*)gb,
                                             (__attribute__((address_space(3))) void*)(dstB + base), 16, 0, 0);
        }
    };

    int buf = 0;
    stage(As[0], Bs[0], 0);
    uint q_cur[8];
    *(u32x4*)&q_cur[0] = *(const u32x4*)(qpw);
    *(u32x4*)&q_cur[4] = *(const u32x4*)(qpw + 4);
    __syncthreads();

    for (int s = 0; s < NSTEPS; s++) {
        uint q_nxt[8];
        if (s + 1 < NSTEPS) {
            stage(As[1 - buf], Bs[1 - buf], (s + 1) * BK);
            const uint* qn = qpw + (size_t)(s + 1) * 512;
            *(u32x4*)&q_nxt[0] = *(const u32x4*)(qn);
            *(u32x4*)&q_nxt[4] = *(const u32x4*)(qn + 4);
        }

        const ushort* Ab = As[buf];
        const float*  Bb = Bs[buf];
#pragma unroll
        for (int kk = 0; kk < BK; kk += 32) {
            int h   = kk >> 5;
            int ckb = (kk >> 3) + quad;      // A-side 16B-chunk column
            short8 a[2], b[4], bd[4];
#pragma unroll
            for (int i = 0; i < 2; i++)
                a[i] = *(const short8*)(Ab + (wm + i * 16 + l16) * BK + (ckb ^ xa) * 8);
#pragma unroll
            for (int jj = 0; jj < 4; jj++) {
                int c0 = (h << 3) + (quad << 1);                 // even global chunk
                const float* rowp = Bb + (wn + jj * 16 + l16) * BK;
                f32x4 f0 = *(const f32x4*)(rowp + ((c0 ^ xa) << 2));
                f32x4 f1 = *(const f32x4*)(rowp + (((c0 + 1) ^ xa) << 2));
                union { u32x4 u; short8 s8v; } bc;
                bc.u.x = cvt2(f0.x, f0.y); bc.u.y = cvt2(f0.z, f0.w);
                bc.u.z = cvt2(f1.x, f1.y); bc.u.w = cvt2(f1.z, f1.w);
                b[jj] = bc.s8v;
            }
#pragma unroll
            for (int jj = 0; jj < 4; jj++)
                bd[jj] = unpack_nib(q_cur[jj * 2 + h]);
#pragma unroll
            for (int i = 0; i < 2; i++)
#pragma unroll
                for (int jj = 0; jj < 4; jj++) {
                    acc_b[i][jj] = __builtin_amdgcn_mfma_f32_16x16x32_bf16(a[i], b[jj],  acc_b[i][jj], 0, 0, 0);
                    acc_d[i][jj] = __builtin_amdgcn_mfma_f32_16x16x32_bf16(a[i], bd[jj], acc_d[i][jj], 0, 0, 0);
                }
        }
        __syncthreads();   // drains next tile's loads + protects buf for re-stage
#pragma unroll
        for (int e = 0; e < 8; e++) q_cur[e] = q_nxt[e];
        buf ^= 1;
    }

    // section select for epilogue scales/zeros
    const int* qz; const float* sc; int r0, Osec;
    if (n0 < N_Q)            { qz = qz_q; sc = sc_q; r0 = n0;                Osec = N_Q;  }
    else if (n0 < N_Q + N_KV){ qz = qz_k; sc = sc_k; r0 = n0 - N_Q;          Osec = N_KV; }
    else                     { qz = qz_v; sc = sc_v; r0 = n0 - (N_Q + N_KV); Osec = N_KV; }

    // epilogue: C/D layout col = lane&15, row = quad*4 + reg  [m89/m91 verified]
    // out = bias + acc_b + s*acc_d - s*(129+z)*rowsumA
    float s4[4], cc4[4], bv4[4];
#pragma unroll
    for (int jj = 0; jj < 4; jj++) {
        int rsec = r0 + wn + jj * 16 + l16;
        float sv = sc[(size_t)d * Osec + rsec];
        int   zq = qz[(size_t)d * (Osec >> 3) + (rsec >> 3)];
        int   z  = (zq >> ((rsec & 7) * 4)) & 0xF;
        s4[jj]  = sv;
        cc4[jj] = sv * (float)(129 + z);
        bv4[jj] = bias[n0 + wn + jj * 16 + l16];
    }
#pragma unroll
    for (int i = 0; i < 2; i++) {
        int toks[4]; float rsv[4];
#pragma unroll
        for (int r = 0; r < 4; r++) {
            int row = m0 + wm + i * 16 + quad * 4 + r;
            toks[r] = perm[row];
            rsv[r]  = rs[row * 2] + rs[row * 2 + 1];
        }
#pragma unroll
        for (int jj = 0; jj < 4; jj++) {
            int col = n0 + wn + jj * 16 + l16;
#pragma unroll
            for (int r = 0; r < 4; r++) {
                int tok = toks[r];
                if (tok >= 0) {
                    float v = bv4[jj] + acc_b[i][jj][r] + s4[jj] * acc_d[i][jj][r] - cc4[jj] * rsv[r];
                    out[(size_t)tok * N_OUT + col] = v;
                }
            }
        }
    }
}

// ---------------------------------------------------------------------------
extern "C" void kernel_launch(void* const* d_in, const int* in_sizes, int n_in,
                              void* d_out, int out_size, void* d_ws, size_t ws_size,
                              hipStream_t stream) {
    const float* x      = (const float*)d_in[0];
    const float* w_base = (const float*)d_in[1];
    const float* bias   = (const float*)d_in[2];
    const int*   qw_q   = (const int*)d_in[3];
    const int*   qw_k   = (const int*)d_in[4];
    const int*   qw_v   = (const int*)d_in[5];
    const int*   qz_q   = (const int*)d_in[6];
    const int*   qz_k   = (const int*)d_in[7];
    const int*   qz_v   = (const int*)d_in[8];
    const float* sc_q   = (const float*)d_in[9];
    const float* sc_k   = (const float*)d_in[10];
    const float* sc_v   = (const float*)d_in[11];
    const int*   indices= (const int*)d_in[12];
    float* out = (float*)d_out;

    // workspace: Xp [1280][4096] bf16 | rs [1280][2] f32 | perm [1280] | pofs
    //          | qp [48][4][2][64][64][8] u32
    char* ws = (char*)d_ws;
    ushort* xp = (ushort*)ws;
    size_t xp_bytes = (size_t)PM_MAX * K_IN * 2;                  // 10485760
    float* rsum = (float*)(ws + xp_bytes);
    size_t rs_bytes = (size_t)PM_MAX * 2 * sizeof(float);         // 10240
    int* perm = (int*)(ws + xp_bytes + rs_bytes);
    int* pofs = perm + PM_MAX;
    uint* qp  = (uint*)(ws + xp_bytes + rs_bytes + PM_MAX * 4 + 64);

    build_perm_kernel<<<1, 1024, 0, stream>>>(indices, perm, pofs);
    prep_kernel<<<NB_RP + NB_XP, 256, 0, stream>>>(
        qw_q, qw_k, qw_v, qp, x, perm, xp, rsum);
    gemm_kernel<<<NBLK, 256, 0, stream>>>(xp, w_base, qp,
        qz_q, qz_k, qz_v, sc_q, sc_k, sc_v, bias,
        perm, pofs, rsum, out);
}

// Round 7
// 363.728 us; speedup vs baseline: 1.2913x; 1.2913x over previous
//
#include <hip/hip_runtime.h>
#include <stdint.h>

// Problem constants (from reference setup_inputs)
#define T_TOK 1024
#define K_IN  4096
#define N_OUT 6144
#define N_Q   4096
#define N_KV  1024
#define N_D   4
#define KP    512          // K_IN/8 packed int32 per row

// GEMM tiling
#define TM 64
#define TN 128
#define BK 64
#define NSTEPS (K_IN / BK)      // 64
#define PM_MAX 1280        // >= 1024 + 4*63 (worst-case 64-padding)
#define MT (PM_MAX/TM)     // 20
#define NT (N_OUT/TN)      // 48
#define NBLK (NT * MT)     // 960

// fused prep kernel block ranges
#define NB_WB ((N_OUT * K_IN / 8) / 256)   // 12288
#define NB_RP (48 * 4 * 2 * 8)             // 3072
#define NB_XP (PM_MAX * 2)                 // 2560

typedef __attribute__((ext_vector_type(8)))  short  short8;   // 8 x bf16 (4 VGPR) MFMA A/B frag
typedef __attribute__((ext_vector_type(4)))  float  float4v;  // MFMA C/D frag
typedef __attribute__((ext_vector_type(4)))  float  f32x4;
typedef __attribute__((ext_vector_type(4)))  uint   u32x4;

__device__ __forceinline__ ushort f2bf(float f) {
    uint32_t u = __float_as_uint(f);
    u = (u + 0x7FFFu + ((u >> 16) & 1u)) >> 16;   // RNE
    return (ushort)u;
}
__device__ __forceinline__ uint pack2(ushort a, ushort b) {
    return (uint)a | ((uint)b << 16);
}

// 8 nibbles of q -> short8 of bf16 values (128 + nib), exact.
// bf16 0x4300 = 128.0; mantissa has 7 bits so 128+n (n<=15) is exact.
// v_perm path (verified on-device r5/r6): e.bj = n_{2j}, o.bj = n_{2j+1};
// word j = perm(o, e, sel_j) | 0x43004300 -> 11 VALU/uint vs ~19 shift/mask.
// The +128 offset and the GPTQ zero-point are corrected in the epilogue
// via the row-sum of A:  s*acc_nib - s*(129+z)*rowsum(A).
__device__ __forceinline__ short8 unpack_nib(uint q) {
    union { u32x4 u; short8 s; } r;
    uint e = q & 0x0F0F0F0Fu;          // even nibbles in byte lanes
    uint o = (q >> 4) & 0x0F0F0F0Fu;   // odd nibbles in byte lanes
    r.u.x = __builtin_amdgcn_perm(o, e, 0x0C040C00u) | 0x43004300u;
    r.u.y = __builtin_amdgcn_perm(o, e, 0x0C050C01u) | 0x43004300u;
    r.u.z = __builtin_amdgcn_perm(o, e, 0x0C060C02u) | 0x43004300u;
    r.u.w = __builtin_amdgcn_perm(o, e, 0x0C070C03u) | 0x43004300u;
    return r.s;
}

// ---------------------------------------------------------------------------
// K1: group tokens by adapter, fully parallel (1024 threads, one per token).
// ---------------------------------------------------------------------------
__global__ void build_perm_kernel(const int* __restrict__ indices,
                                  int* __restrict__ perm,
                                  int* __restrict__ pofs) {
    __shared__ int cw[16][4];   // per-wave counts
    __shared__ int pw[16][4];   // exclusive wave prefixes
    __shared__ int ps[N_D + 1];
    int tid = threadIdx.x;      // 1024 threads
    for (int p = tid; p < PM_MAX; p += 1024) perm[p] = -1;

    int d = indices[tid];
    unsigned long long m[4];
    m[0] = __ballot(d == 0); m[1] = __ballot(d == 1);
    m[2] = __ballot(d == 2); m[3] = __ballot(d == 3);
    int lane = tid & 63, wv = tid >> 6;
    if (lane < 4) cw[wv][lane] = (int)__popcll(m[lane]);
    __syncthreads();
    if (tid == 0) {
        int tot[4] = {0, 0, 0, 0};
        for (int w = 0; w < 16; w++)
            for (int dd = 0; dd < 4; dd++) { pw[w][dd] = tot[dd]; tot[dd] += cw[w][dd]; }
        int run = 0;
        for (int dd = 0; dd < N_D; dd++) { ps[dd] = run; run += ((tot[dd] + TM - 1) / TM) * TM; }
        ps[N_D] = run;
        for (int dd = 0; dd <= N_D; dd++) pofs[dd] = ps[dd];
    }
    __syncthreads();
    unsigned long long lt = (1ull << lane) - 1ull;
    int rank = pw[wv][d] + (int)__popcll(m[d] & lt);
    perm[ps[d] + rank] = tid;
}

// ---------------------------------------------------------------------------
// K2 (fused prep): three independent jobs partitioned by blockIdx range.
//  [0, NB_WB):      wb16[o][k] = bf16(w_base[o][k])
//  [NB_WB,+NB_RP):  repack qw -> qp in GEMM-lane order
//  [..,+NB_XP):     Xp[pm][k] = bf16(x[perm[pm]][k]) + row-sums rs
// ---------------------------------------------------------------------------
__global__ void prep_kernel(const float* __restrict__ w_base, ushort* __restrict__ wb16,
                            const int* __restrict__ qw_q, const int* __restrict__ qw_k,
                            const int* __restrict__ qw_v, uint* __restrict__ qp,
                            const float* __restrict__ x, const int* __restrict__ perm,
                            ushort* __restrict__ xp, float* __restrict__ rs) {
    __shared__ int slds[64 * 64];
    int tid = threadIdx.x;
    int b = blockIdx.x;

    if (b < NB_WB) {
        // ---- wbconv ----
        int id = b * 256 + tid;                 // [0, N_OUT*K_IN/8)
        const f32x4* src = (const f32x4*)(w_base + (size_t)id * 8);
        f32x4 a = __builtin_nontemporal_load(src);
        f32x4 c = __builtin_nontemporal_load(src + 1);
        u32x4 packv;
        packv.x = pack2(f2bf(a.x), f2bf(a.y));
        packv.y = pack2(f2bf(a.z), f2bf(a.w));
        packv.z = pack2(f2bf(c.x), f2bf(c.y));
        packv.w = pack2(f2bf(c.z), f2bf(c.w));
        *(u32x4*)(wb16 + (size_t)id * 8) = packv;
        return;
    }
    b -= NB_WB;
    if (b < NB_RP) {
        // ---- repack qw: qp[bn][d][w2][s][lane][8], block = (bn,d,w2,s8) ----
        int s8 = b & 7;
        int r  = b >> 3;
        int w2 = r & 1; r >>= 1;
        int d  = r & 3;
        int bn = r >> 2;
        const int* qw; int r0, Osec;
        if (bn < 32)      { qw = qw_q; r0 = bn * 128;        Osec = N_Q;  }
        else if (bn < 40) { qw = qw_k; r0 = (bn - 32) * 128; Osec = N_KV; }
        else              { qw = qw_v; r0 = (bn - 40) * 128; Osec = N_KV; }
#pragma unroll
        for (int k = 0; k < 4; k++) {
            int p   = k * 256 + tid;       // dwordx4 index [0,1024)
            int row = p >> 4, c4 = p & 15;
            const int* src = qw + ((size_t)d * Osec + r0 + w2 * 64 + row) * KP + s8 * 64 + c4 * 4;
            *(u32x4*)&slds[row * 64 + c4 * 4] = *(const u32x4*)src;
        }
        __syncthreads();
        size_t obase = (size_t)b * 4096;   // 4096 uints per block slab
#pragma unroll
        for (int k = 0; k < 2; k++) {
            int p    = k * 256 + tid;      // packet index [0,512)
            int sl   = p >> 6, lane = p & 63;
            int quad = lane >> 4, l16 = lane & 15;
            uint pk[8];
#pragma unroll
            for (int e = 0; e < 8; e++) {
                int jj = e >> 1, h = e & 1;
                pk[e] = (uint)slds[(jj * 16 + l16) * 64 + sl * 8 + h * 4 + quad];
            }
            *(u32x4*)(qp + obase + (size_t)p * 8)     = *(u32x4*)&pk[0];
            *(u32x4*)(qp + obase + (size_t)p * 8 + 4) = *(u32x4*)&pk[4];
        }
        return;
    }
    b -= NB_RP;
    {
        // ---- build_xp ----
        int pm = b >> 1;
        int half = b & 1;
        int c0 = half * (K_IN / 2) + tid * 8;
        int tok = perm[pm];
        ushort res[8];
        if (tok < 0) {
#pragma unroll
            for (int j = 0; j < 8; j++) res[j] = 0;
        } else {
            const f32x4* src = (const f32x4*)(x + (size_t)tok * K_IN + c0);
            f32x4 a = __builtin_nontemporal_load(src);
            f32x4 c = __builtin_nontemporal_load(src + 1);
            float v[8] = {a.x, a.y, a.z, a.w, c.x, c.y, c.z, c.w};
#pragma unroll
            for (int j = 0; j < 8; j++) res[j] = f2bf(v[j]);
        }
        u32x4 packv;
        packv.x = pack2(res[0], res[1]); packv.y = pack2(res[2], res[3]);
        packv.z = pack2(res[4], res[5]); packv.w = pack2(res[6], res[7]);
        *(u32x4*)(xp + (size_t)pm * K_IN + c0) = packv;

        float ssum = 0.f;
#pragma unroll
        for (int j = 0; j < 8; j++) ssum += __uint_as_float((uint)res[j] << 16);
#pragma unroll
        for (int off = 32; off > 0; off >>= 1) ssum += __shfl_xor(ssum, off);
        float* wsum = (float*)slds;
        if ((tid & 63) == 0) wsum[tid >> 6] = ssum;
        __syncthreads();
        if (tid == 0) rs[pm * 2 + half] = wsum[0] + wsum[1] + wsum[2] + wsum[3];
    }
}

// ---------------------------------------------------------------------------
// K3: full-K GEMM with fused GPTQ delta, 3-buffer distance-2 pipeline.
// Per step: issue q-prefetch (2 loads) + stage step s+2 (6 global_load_lds),
// compute step s, then s_waitcnt vmcnt(8) + raw s_barrier: the 8 just-issued
// loads stay in flight across the barrier; only the distance-1 stage drains.
// In-order vmcnt retirement makes vmcnt(8) guarantee stage(s+1) complete
// regardless of intra-iteration issue order (correctness is order-free).
// Delta path: repacked qp packets unpacked with v_perm (11 VALU/uint).
// Epilogue: out = bias + acc_base + s*acc_nib - s*(129+z)*rowsumA.
// ---------------------------------------------------------------------------
__global__ __launch_bounds__(256, 2) void gemm_kernel(
    const ushort* __restrict__ xp, const ushort* __restrict__ wb16,
    const uint* __restrict__ qp,
    const int* __restrict__ qz_q, const int* __restrict__ qz_k, const int* __restrict__ qz_v,
    const float* __restrict__ sc_q, const float* __restrict__ sc_k, const float* __restrict__ sc_v,
    const float* __restrict__ bias,
    const int* __restrict__ perm, const int* __restrict__ pofs,
    const float* __restrict__ rs,
    float* __restrict__ out) {

    __shared__ ushort As[3][TM * BK];   // 3 x 8 KB  (bf16 A)
    __shared__ ushort Bs[3][TN * BK];   // 3 x 16 KB (bf16 base B) -> 72 KB total

    // XCD-pinned decode: all blocks of one bn share lin%8 -> same XCD L2.
    int lin  = blockIdx.x;              // [0, 960)
    int low3 = lin & 7, rest = lin >> 3;
    int bm   = rest % MT, bq = rest / MT;
    int bn   = bq * 8 + low3;

    int m0 = bm * TM, n0 = bn * TN;
    int ptot = pofs[N_D];
    if (m0 >= ptot) return;                       // uniform per block
    int d = 0;
    while (d < N_D - 1 && m0 >= pofs[d + 1]) d++; // tile fully inside segment d

    int tid  = threadIdx.x;
    int lane = tid & 63;
    int wv   = tid >> 6;
    int wm   = (wv & 1) * 32;
    int wn   = (wv >> 1) * 64;
    int quad = lane >> 4;
    int l16  = lane & 15;
    int xa   = l16 & 7;          // read-side swizzle term (0-conflict pattern, r2-r4)

    // delta packet base for this wave: qp[bn][d][w2][s][lane][8]
    const uint* qpw = qp + (((size_t)(bn * 4 + d) * 2 + (wv >> 1)) * 64 * 64 * 8)
                         + (size_t)lane * 8;

    const float4v zero4 = {0.f, 0.f, 0.f, 0.f};
    float4v acc_b[2][4], acc_d[2][4];
#pragma unroll
    for (int i = 0; i < 2; i++)
#pragma unroll
        for (int jj = 0; jj < 4; jj++) { acc_b[i][jj] = zero4; acc_d[i][jj] = zero4; }

    // stage one BK-tile (A+B bf16) into LDS buffer; 16B/lane, chunk^(row&7)
    // source swizzle (LDS dest linear per global_load_lds). 6 loads/thread.
    auto stage = [&](ushort* dstA, ushort* dstB, int k0) {
#pragma unroll
        for (int w = 0; w < 2; w++) {
            int p   = w * 256 + tid;
            int row = p >> 3;
            int ckl = (p & 7) ^ (row & 7);
            const ushort* ga = xp + (size_t)(m0 + row) * K_IN + k0 + ckl * 8;
            int base = (w * 256 + (tid & ~63)) * 8;
            __builtin_amdgcn_global_load_lds((const __attribute__((address_space(1))) void*)ga,
                                             (__attribute__((address_space(3))) void*)(dstA + base), 16, 0, 0);
        }
#pragma unroll
        for (int w = 0; w < 4; w++) {
            int p   = w * 256 + tid;
            int row = p >> 3;
            int ckl = (p & 7) ^ (row & 7);
            const ushort* gb = wb16 + (size_t)(n0 + row) * K_IN + k0 + ckl * 8;
            int base = (w * 256 + (tid & ~63)) * 8;
            __builtin_amdgcn_global_load_lds((const __attribute__((address_space(1))) void*)gb,
                                             (__attribute__((address_space(3))) void*)(dstB + base), 16, 0, 0);
        }
    };

    auto qload = [&](uint* qdst, int step) {
        const uint* qn = qpw + (size_t)step * 512;
        *(u32x4*)&qdst[0] = *(const u32x4*)(qn);
        *(u32x4*)&qdst[4] = *(const u32x4*)(qn + 4);
    };

    auto compute = [&](const ushort* Ab, const ushort* Bb, const uint* qc) {
#pragma unroll
        for (int kk = 0; kk < BK; kk += 32) {
            int h   = kk >> 5;
            int ckb = (kk >> 3) + quad;      // 16B-chunk column wanted
            short8 a[2], b[4], bd[4];
#pragma unroll
            for (int i = 0; i < 2; i++)
                a[i] = *(const short8*)(Ab + (wm + i * 16 + l16) * BK + ((ckb ^ xa) * 8));
#pragma unroll
            for (int jj = 0; jj < 4; jj++)
                b[jj] = *(const short8*)(Bb + (wn + jj * 16 + l16) * BK + ((ckb ^ xa) * 8));
#pragma unroll
            for (int jj = 0; jj < 4; jj++)
                bd[jj] = unpack_nib(qc[jj * 2 + h]);
#pragma unroll
            for (int i = 0; i < 2; i++)
#pragma unroll
                for (int jj = 0; jj < 4; jj++) {
                    acc_b[i][jj] = __builtin_amdgcn_mfma_f32_16x16x32_bf16(a[i], b[jj],  acc_b[i][jj], 0, 0, 0);
                    acc_d[i][jj] = __builtin_amdgcn_mfma_f32_16x16x32_bf16(a[i], bd[jj], acc_d[i][jj], 0, 0, 0);
                }
        }
    };

    uint qA[8], qB[8];

    // Prologue: q(0) first, then stage(0), stage(1).  vmcnt(6) drains q(0)+
    // stage(0) (oldest 8) and leaves stage(1) in flight across the barrier.
    qload(qA, 0);
    stage(As[0], Bs[0], 0);
    stage(As[1], Bs[1], BK);
    asm volatile("s_waitcnt vmcnt(6)" ::: "memory");
    __builtin_amdgcn_s_barrier();

    int b0 = 0, b1 = 1, b2 = 2;
#pragma unroll 1
    for (int s = 0; s < NSTEPS; s += 2) {
        // ---- even step s: compute buf b0 with qA; prefetch q(s+1)->qB, stage(s+2)->b2
        qload(qB, s + 1);                       // s+1 <= 63 always valid here
        __builtin_amdgcn_sched_barrier(0);      // pin q-issue before stage-issue
        if (s + 2 < NSTEPS) stage(As[b2], Bs[b2], (s + 2) * BK);
        compute(As[b0], Bs[b0], qA);
        if (s < NSTEPS - 2)       asm volatile("s_waitcnt vmcnt(8)" ::: "memory");
        else                      asm volatile("s_waitcnt vmcnt(2)" ::: "memory");
        __builtin_amdgcn_s_barrier();

        // ---- odd step s+1: compute buf b1 with qB; prefetch q(s+2)->qA, stage(s+3)->b0
        if (s + 2 < NSTEPS) {
            qload(qA, s + 2);
            __builtin_amdgcn_sched_barrier(0);
        }
        if (s + 3 < NSTEPS) stage(As[b0], Bs[b0], (s + 3) * BK);
        compute(As[b1], Bs[b1], qB);
        if (s + 1 < NSTEPS - 2)      asm volatile("s_waitcnt vmcnt(8)" ::: "memory");
        else if (s + 1 == NSTEPS - 2) asm volatile("s_waitcnt vmcnt(2)" ::: "memory");
        if (s + 1 < NSTEPS - 1) __builtin_amdgcn_s_barrier();

        int t = b0; b0 = b2; b2 = b1; b1 = t;   // (b0,b1,b2) <- (b2,b0,b1)
    }

    // section select for epilogue scales/zeros
    const int* qz; const float* sc; int r0, Osec;
    if (n0 < N_Q)            { qz = qz_q; sc = sc_q; r0 = n0;                Osec = N_Q;  }
    else if (n0 < N_Q + N_KV){ qz = qz_k; sc = sc_k; r0 = n0 - N_Q;          Osec = N_KV; }
    else                     { qz = qz_v; sc = sc_v; r0 = n0 - (N_Q + N_KV); Osec = N_KV; }

    // epilogue: C/D layout col = lane&15, row = quad*4 + reg  [m89/m91 verified]
    // out = bias + acc_b + s*acc_d - s*(129+z)*rowsumA
    float s4[4], cc4[4], bv4[4];
#pragma unroll
    for (int jj = 0; jj < 4; jj++) {
        int rsec = r0 + wn + jj * 16 + l16;
        float sv = sc[(size_t)d * Osec + rsec];
        int   zq = qz[(size_t)d * (Osec >> 3) + (rsec >> 3)];
        int   z  = (zq >> ((rsec & 7) * 4)) & 0xF;
        s4[jj]  = sv;
        cc4[jj] = sv * (float)(129 + z);
        bv4[jj] = bias[n0 + wn + jj * 16 + l16];
    }
#pragma unroll
    for (int i = 0; i < 2; i++) {
        int toks[4]; float rsv[4];
#pragma unroll
        for (int r = 0; r < 4; r++) {
            int row = m0 + wm + i * 16 + quad * 4 + r;
            toks[r] = perm[row];
            rsv[r]  = rs[row * 2] + rs[row * 2 + 1];
        }
#pragma unroll
        for (int jj = 0; jj < 4; jj++) {
            int col = n0 + wn + jj * 16 + l16;
#pragma unroll
            for (int r = 0; r < 4; r++) {
                int tok = toks[r];
                if (tok >= 0) {
                    float v = bv4[jj] + acc_b[i][jj][r] + s4[jj] * acc_d[i][jj][r] - cc4[jj] * rsv[r];
                    out[(size_t)tok * N_OUT + col] = v;
                }
            }
        }
    }
}

// ---------------------------------------------------------------------------
extern "C" void kernel_launch(void* const* d_in, const int* in_sizes, int n_in,
                              void* d_out, int out_size, void* d_ws, size_t ws_size,
                              hipStream_t stream) {
    const float* x      = (const float*)d_in[0];
    const float* w_base = (const float*)d_in[1];
    const float* bias   = (const float*)d_in[2];
    const int*   qw_q   = (const int*)d_in[3];
    const int*   qw_k   = (const int*)d_in[4];
    const int*   qw_v   = (const int*)d_in[5];
    const int*   qz_q   = (const int*)d_in[6];
    const int*   qz_k   = (const int*)d_in[7];
    const int*   qz_v   = (const int*)d_in[8];
    const float* sc_q   = (const float*)d_in[9];
    const float* sc_k   = (const float*)d_in[10];
    const float* sc_v   = (const float*)d_in[11];
    const int*   indices= (const int*)d_in[12];
    float* out = (float*)d_out;

    // workspace: wb16 [6144][4096] bf16 | Xp [1280][4096] bf16 | rs [1280][2] f32
    //          | perm [1280] | pofs | qp [48][4][2][64][64][8] u32
    char* ws = (char*)d_ws;
    ushort* wb16 = (ushort*)ws;
    size_t wb_bytes = (size_t)N_OUT * K_IN * 2;                   // 50331648
    ushort* xp = (ushort*)(ws + wb_bytes);
    size_t xp_bytes = (size_t)PM_MAX * K_IN * 2;                  // 10485760
    float* rsum = (float*)(ws + wb_bytes + xp_bytes);
    size_t rs_bytes = (size_t)PM_MAX * 2 * sizeof(float);         // 10240
    int* perm = (int*)(ws + wb_bytes + xp_bytes + rs_bytes);
    int* pofs = perm + PM_MAX;
    uint* qp  = (uint*)(ws + wb_bytes + xp_bytes + rs_bytes + PM_MAX * 4 + 64);

    build_perm_kernel<<<1, 1024, 0, stream>>>(indices, perm, pofs);
    prep_kernel<<<NB_WB + NB_RP + NB_XP, 256, 0, stream>>>(
        w_base, wb16, qw_q, qw_k, qw_v, qp, x, perm, xp, rsum);
    gemm_kernel<<<NBLK, 256, 0, stream>>>(xp, wb16, qp,
        qz_q, qz_k, qz_v, sc_q, sc_k, sc_v, bias,
        perm, pofs, rsum, out);
}